// Round 1
// baseline (206.733 us; speedup 1.0000x reference)
//
#include <hip/hip_runtime.h>
#include <stdint.h>

#define S_LEN 80
#define H_DIM 128
#define ROWS 10      // lane rows per block (2560 = 256 blocks * 10)
#define MROWS 16     // padded MFMA M-tile
#define BLOCK_T 512  // 8 waves

typedef __bf16 bf16x8 __attribute__((ext_vector_type(8)));
typedef unsigned short u16x8 __attribute__((ext_vector_type(8)));
typedef unsigned short u16x4 __attribute__((ext_vector_type(4)));
typedef float f32x4 __attribute__((ext_vector_type(4)));

__device__ __forceinline__ unsigned short f2bf(float f) {
    uint32_t u = __builtin_bit_cast(uint32_t, f);
    u += 0x7FFFu + ((u >> 16) & 1u);   // round-to-nearest-even
    return (unsigned short)(u >> 16);
}
__device__ __forceinline__ float sigf(float x) { return 1.0f / (1.0f + __expf(-x)); }
__device__ __forceinline__ float thf(float x)  { return 2.0f / (1.0f + __expf(-2.0f * x)) - 1.0f; }

// One block = 10 lane rows through all 80 LSTM steps. 8 waves; wave w owns gate
// columns [w*64, w*64+64). W_ih/W_hh slices live in VGPRs as bf16 MFMA B-frags.
__global__ __launch_bounds__(BLOCK_T, 2)
void lane_lstm(const float* __restrict__ lanes,
               const float* __restrict__ W_emb, const float* __restrict__ b_emb,
               const float* __restrict__ W_ih,  const float* __restrict__ W_hh,
               const float* __restrict__ b_ih,  const float* __restrict__ b_hh,
               float* __restrict__ out, int BL)
{
    __shared__ __align__(16) float ext_lds[S_LEN * ROWS * 5];     // 16000 B
    __shared__ __align__(16) float gates_lds[MROWS][516];         // 33024 B (pad +4)
    __shared__ __align__(16) unsigned short h_lds[MROWS * H_DIM]; // 4096 B bf16
    __shared__ __align__(16) unsigned short emb_lds[MROWS * H_DIM];
    __shared__ int valid_lds[MROWS];

    const int t    = threadIdx.x;
    const int lane = t & 63;
    const int wv   = t >> 6;
    const int row0 = blockIdx.x * ROWS;

    if (t < MROWS) valid_lds[t] = 1;
    for (int i = t; i < MROWS * H_DIM; i += BLOCK_T) h_lds[i] = 0;  // h0 = 0
    __syncthreads();

    // ---- precompute ext features (x,y,dx,dy,yaw) for all (s,row) + NaN flags ----
    for (int p = t; p < S_LEN * ROWS; p += BLOCK_T) {
        int s = p % S_LEN;
        int r = p / S_LEN;
        int bl = row0 + r;
        float x = 0.f, y = 0.f, xp = 0.f, yp = 0.f;
        if (bl < BL) {
            const float* lp = lanes + ((size_t)s * BL + bl) * 2;
            x = lp[0]; y = lp[1];
            if (s > 0) { const float* lq = lanes + ((size_t)(s - 1) * BL + bl) * 2; xp = lq[0]; yp = lq[1]; }
            else       { xp = x; yp = y; }
        }
        float* e = &ext_lds[(s * ROWS + r) * 5];
        e[0] = x; e[1] = y; e[2] = x - xp; e[3] = y - yp; e[4] = atan2f(y, x);
        if (__builtin_isnan(x) || __builtin_isnan(y)) valid_lds[r] = 0;
    }

    // ---- per-thread elementwise constants (thread t -> row t>>5, hcols (t&31)*4..+3) ----
    const int r_ew = t >> 5;
    const int hc0  = (t & 31) << 2;
    float wemb[4][5], bemb[4], bia[4][4];   // bia[gate i,f,g,o][j]
    #pragma unroll
    for (int j = 0; j < 4; ++j) {
        int hc = hc0 + j;
        #pragma unroll
        for (int d = 0; d < 5; ++d) wemb[j][d] = W_emb[hc * 5 + d];
        bemb[j] = b_emb[hc];
        #pragma unroll
        for (int g = 0; g < 4; ++g) bia[g][j] = b_ih[g * H_DIM + hc] + b_hh[g * H_DIM + hc];
    }

    // ---- load weight B-fragments into registers (bf16), wave-owned N-slice ----
    // B-frag slot map: col = w*64 + nt*16 + (lane&15), k = kt*32 + (lane>>4)*8 + j.
    // Same (lane,j)->k map used for A-frags => any HW k-permutation cancels.
    bf16x8 wih[4][4], whh[4][4];
    {
        const int colb = wv * 64 + (lane & 15);
        const int kb0  = (lane >> 4) << 3;
        #pragma unroll
        for (int nt = 0; nt < 4; ++nt) {
            #pragma unroll
            for (int kt = 0; kt < 4; ++kt) {
                const int col = colb + nt * 16;
                const int kb  = kb0 + kt * 32;
                const float* pa = &W_ih[col * H_DIM + kb];
                const float* pb = &W_hh[col * H_DIM + kb];
                u16x8 ta, tb;
                #pragma unroll
                for (int j = 0; j < 8; ++j) { ta[j] = f2bf(pa[j]); tb[j] = f2bf(pb[j]); }
                wih[nt][kt] = __builtin_bit_cast(bf16x8, ta);
                whh[nt][kt] = __builtin_bit_cast(bf16x8, tb);
            }
        }
    }

    float c0 = 0.f, c1 = 0.f, c2 = 0.f, c3 = 0.f;
    const bool rvalid = (r_ew < ROWS) && (row0 + r_ew < BL);

    __syncthreads();

    for (int s = 0; s < S_LEN; ++s) {
        // ---- P1: emb[s] = relu(W_emb @ ext + b_emb), bf16 into swizzled LDS ----
        if (rvalid) {
            const float* e = &ext_lds[(s * ROWS + r_ew) * 5];
            float x0 = e[0], x1 = e[1], x2 = e[2], x3 = e[3], x4 = e[4];
            if (!valid_lds[r_ew]) { x0 = x1 = x2 = x3 = x4 = 0.f; }  // invalid lane -> ext = 0
            u16x4 ev;
            #pragma unroll
            for (int j = 0; j < 4; ++j) {
                float a = bemb[j];
                a += wemb[j][0] * x0; a += wemb[j][1] * x1; a += wemb[j][2] * x2;
                a += wemb[j][3] * x3; a += wemb[j][4] * x4;
                ev[j] = f2bf(fmaxf(a, 0.f));
            }
            int byte = (r_ew << 8) + (hc0 << 1);
            byte ^= (r_ew & 7) << 4;             // XOR swizzle (G4) — add first, then XOR
            *(u16x4*)((char*)&emb_lds[0] + byte) = ev;
        }
        __syncthreads();

        // ---- P2: gates = emb @ W_ih^T + h @ W_hh^T  (MFMA, fp32 accum) ----
        f32x4 ac0 = {0.f,0.f,0.f,0.f}, ac1 = {0.f,0.f,0.f,0.f};
        f32x4 ac2 = {0.f,0.f,0.f,0.f}, ac3 = {0.f,0.f,0.f,0.f};
        {
            const int arow = lane & 15;
            const int akb  = (lane >> 4) << 3;
            #pragma unroll
            for (int kt = 0; kt < 4; ++kt) {
                int byte = (arow << 8) + ((kt * 32 + akb) << 1);
                byte ^= (arow & 7) << 4;
                bf16x8 ae = *(const bf16x8*)((const char*)&emb_lds[0] + byte);
                bf16x8 ah = *(const bf16x8*)((const char*)&h_lds[0]   + byte);
                ac0 = __builtin_amdgcn_mfma_f32_16x16x32_bf16(ae, wih[0][kt], ac0, 0, 0, 0);
                ac0 = __builtin_amdgcn_mfma_f32_16x16x32_bf16(ah, whh[0][kt], ac0, 0, 0, 0);
                ac1 = __builtin_amdgcn_mfma_f32_16x16x32_bf16(ae, wih[1][kt], ac1, 0, 0, 0);
                ac1 = __builtin_amdgcn_mfma_f32_16x16x32_bf16(ah, whh[1][kt], ac1, 0, 0, 0);
                ac2 = __builtin_amdgcn_mfma_f32_16x16x32_bf16(ae, wih[2][kt], ac2, 0, 0, 0);
                ac2 = __builtin_amdgcn_mfma_f32_16x16x32_bf16(ah, whh[2][kt], ac2, 0, 0, 0);
                ac3 = __builtin_amdgcn_mfma_f32_16x16x32_bf16(ae, wih[3][kt], ac3, 0, 0, 0);
                ac3 = __builtin_amdgcn_mfma_f32_16x16x32_bf16(ah, whh[3][kt], ac3, 0, 0, 0);
            }
        }
        {   // C/D map (m89-verified): col = lane&15, row = (lane>>4)*4 + reg
            const int crow = (lane >> 4) << 2;
            const int ccol = wv * 64 + (lane & 15);
            #pragma unroll
            for (int i = 0; i < 4; ++i) {
                gates_lds[crow + i][ccol]      = ac0[i];
                gates_lds[crow + i][ccol + 16] = ac1[i];
                gates_lds[crow + i][ccol + 32] = ac2[i];
                gates_lds[crow + i][ccol + 48] = ac3[i];
            }
        }
        __syncthreads();

        // ---- P3: LSTM cell, c in registers, h -> bf16 LDS (and out at s=79) ----
        if (rvalid) {
            const float* gp = &gates_lds[r_ew][0];
            f32x4 iv = *(const f32x4*)(gp + hc0);
            f32x4 fv = *(const f32x4*)(gp + H_DIM + hc0);
            f32x4 gv = *(const f32x4*)(gp + 2 * H_DIM + hc0);
            f32x4 ov = *(const f32x4*)(gp + 3 * H_DIM + hc0);
            f32x4 hv;
            float cn;
            cn = sigf(fv[0] + bia[1][0]) * c0 + sigf(iv[0] + bia[0][0]) * thf(gv[0] + bia[2][0]);
            c0 = cn; hv[0] = sigf(ov[0] + bia[3][0]) * thf(cn);
            cn = sigf(fv[1] + bia[1][1]) * c1 + sigf(iv[1] + bia[0][1]) * thf(gv[1] + bia[2][1]);
            c1 = cn; hv[1] = sigf(ov[1] + bia[3][1]) * thf(cn);
            cn = sigf(fv[2] + bia[1][2]) * c2 + sigf(iv[2] + bia[0][2]) * thf(gv[2] + bia[2][2]);
            c2 = cn; hv[2] = sigf(ov[2] + bia[3][2]) * thf(cn);
            cn = sigf(fv[3] + bia[1][3]) * c3 + sigf(iv[3] + bia[0][3]) * thf(gv[3] + bia[2][3]);
            c3 = cn; hv[3] = sigf(ov[3] + bia[3][3]) * thf(cn);

            u16x4 hb;
            hb[0] = f2bf(hv[0]); hb[1] = f2bf(hv[1]); hb[2] = f2bf(hv[2]); hb[3] = f2bf(hv[3]);
            int byte = (r_ew << 8) + (hc0 << 1);
            byte ^= (r_ew & 7) << 4;
            *(u16x4*)((char*)&h_lds[0] + byte) = hb;

            if (s == S_LEN - 1) {
                *(f32x4*)(out + (size_t)(row0 + r_ew) * H_DIM + hc0) = hv;
            }
        }
        __syncthreads();
    }
}

extern "C" void kernel_launch(void* const* d_in, const int* in_sizes, int n_in,
                              void* d_out, int out_size, void* d_ws, size_t ws_size,
                              hipStream_t stream) {
    const float* lanes = (const float*)d_in[1];
    const float* W_emb = (const float*)d_in[2];
    const float* b_emb = (const float*)d_in[3];
    const float* W_ih  = (const float*)d_in[4];
    const float* W_hh  = (const float*)d_in[5];
    const float* b_ih  = (const float*)d_in[6];
    const float* b_hh  = (const float*)d_in[7];
    float* out = (float*)d_out;

    const int BL   = in_sizes[1] / (2 * S_LEN);   // 2560
    const int grid = (BL + ROWS - 1) / ROWS;      // 256 blocks -> 1 per CU

    lane_lstm<<<dim3(grid), dim3(BLOCK_T), 0, stream>>>(
        lanes, W_emb, b_emb, W_ih, W_hh, b_ih, b_hh, out, BL);
}

// Round 3
// 146.441 us; speedup vs baseline: 1.4117x; 1.4117x over previous
//
#include <hip/hip_runtime.h>
#include <stdint.h>

#define S_LEN 80
#define H_DIM 128
#define ROWS 10      // real lane rows per block (2560 = 256 blocks * 10)
#define MROWS 16     // padded MFMA M-tile
#define BLOCK_T 512  // 8 waves

typedef __bf16 bf16x8 __attribute__((ext_vector_type(8)));
typedef unsigned short u16x8 __attribute__((ext_vector_type(8)));
typedef unsigned short u16x4 __attribute__((ext_vector_type(4)));
typedef float f32x4 __attribute__((ext_vector_type(4)));

__device__ __forceinline__ unsigned short f2bf(float f) {
    uint32_t u = __builtin_bit_cast(uint32_t, f);
    u += 0x7FFFu + ((u >> 16) & 1u);   // round-to-nearest-even
    return (unsigned short)(u >> 16);
}
__device__ __forceinline__ float sigf(float x) {
    return __builtin_amdgcn_rcpf(1.0f + __expf(-x));
}
__device__ __forceinline__ float thf(float x) {
    return 2.0f * __builtin_amdgcn_rcpf(1.0f + __expf(-2.0f * x)) - 1.0f;
}

// One block = 10 lane rows through 80 LSTM steps. 8 waves; wave w owns hcols
// [w*16, w*16+16) with ALL FOUR gates (N-tiles at cols g*128 + w*16) so the
// cell update is wave-local in registers. One barrier per step, double-buffered
// h/emb LDS. W_ih/W_hh slices pinned in regs as bf16 MFMA B-frags.
//
// Swizzle discipline: key = (row&7)<<4 spans BITS 4-6. It must be XORed onto
// the FULL logical byte offset (incl. the kt*64 term, bits 6-7). Pre-XORing a
// base and adding kt*64 afterwards is WRONG for rows with (row&7)>=4 — that
// was round 2's correctness bug.
__global__ __launch_bounds__(BLOCK_T, 2)
void lane_lstm(const float* __restrict__ lanes,
               const float* __restrict__ W_emb, const float* __restrict__ b_emb,
               const float* __restrict__ W_ih,  const float* __restrict__ W_hh,
               const float* __restrict__ b_ih,  const float* __restrict__ b_hh,
               float* __restrict__ out, int BL)
{
    __shared__ __align__(16) float ext_lds[S_LEN * ROWS * 5];           // 16000 B
    __shared__ __align__(16) unsigned short emb_lds[2][MROWS * H_DIM];  // 2x4096 B
    __shared__ __align__(16) unsigned short h_lds[2][MROWS * H_DIM];    // 2x4096 B
    __shared__ int valid_lds[MROWS];

    const int t    = threadIdx.x;
    const int lane = t & 63;
    const int wv   = t >> 6;
    const int row0 = blockIdx.x * ROWS;

    if (t < MROWS) valid_lds[t] = 1;
    {   // h0 = 0 (buffer 0): 512 threads x 8 B = 4096 B
        u16x4 z = {0, 0, 0, 0};
        *(u16x4*)((char*)&h_lds[0][0] + t * 8) = z;
    }
    __syncthreads();   // valid init visible before NaN-clears below

    // ---- ext features (x,y,dx,dy,yaw); consecutive p -> consecutive r (coalesced) ----
    for (int p = t; p < S_LEN * ROWS; p += BLOCK_T) {
        int s = p / ROWS;
        int r = p - s * ROWS;
        int bl = row0 + r;
        float x = 0.f, y = 0.f, dx = 0.f, dy = 0.f;
        if (bl < BL) {
            const float* lp = lanes + ((size_t)s * BL + bl) * 2;
            x = lp[0]; y = lp[1];
            if (s > 0) {
                const float* lq = lanes + ((size_t)(s - 1) * BL + bl) * 2;
                dx = x - lq[0]; dy = y - lq[1];
            }
            if (__builtin_isnan(x) || __builtin_isnan(y)) valid_lds[r] = 0;
        }
        float* e = &ext_lds[p * 5];
        e[0] = x; e[1] = y; e[2] = dx; e[3] = dy; e[4] = atan2f(y, x);
    }

    // ---- wave-owned weight B-frags (bf16) + folded bias ----
    // B-frag: col = g*128 + wv*16 + (lane&15), k = kt*32 + (lane>>4)*8 + j.
    // Same (lane,j)->k map as A-frags => HW k-permutation cancels.
    const int hcol = wv * 16 + (lane & 15);
    const int kb0  = (lane >> 4) << 3;
    bf16x8 wih[4][4], whh[4][4];
    float bia[4];
    #pragma unroll
    for (int g = 0; g < 4; ++g) {
        bia[g] = b_ih[g * H_DIM + hcol] + b_hh[g * H_DIM + hcol];
        #pragma unroll
        for (int kt = 0; kt < 4; ++kt) {
            const float* pa = &W_ih[(size_t)(g * H_DIM + hcol) * H_DIM + kt * 32 + kb0];
            const float* pb = &W_hh[(size_t)(g * H_DIM + hcol) * H_DIM + kt * 32 + kb0];
            u16x8 ta, tb;
            #pragma unroll
            for (int j = 0; j < 8; ++j) { ta[j] = f2bf(pa[j]); tb[j] = f2bf(pb[j]); }
            wih[g][kt] = __builtin_bit_cast(bf16x8, ta);
            whh[g][kt] = __builtin_bit_cast(bf16x8, tb);
        }
    }

    // ---- per-thread emb constants (thread t -> row t>>5, hcols (t&31)*4..+3) ----
    const int er  = t >> 5;
    const int ec0 = (t & 31) << 2;
    float wemb[4][5], bemb[4];
    #pragma unroll
    for (int j = 0; j < 4; ++j) {
        #pragma unroll
        for (int d = 0; d < 5; ++d) wemb[j][d] = W_emb[(ec0 + j) * 5 + d];
        bemb[j] = b_emb[ec0 + j];
    }
    const int ebyte = ((er << 8) + (ec0 << 1)) ^ ((er & 7) << 4);   // full-offset XOR

    auto emb_store = [&](int s, int b) {
        float x0 = 0.f, x1 = 0.f, x2 = 0.f, x3 = 0.f, x4 = 0.f;
        if (er < ROWS && valid_lds[er] && row0 + er < BL) {
            const float* e = &ext_lds[(s * ROWS + er) * 5];
            x0 = e[0]; x1 = e[1]; x2 = e[2]; x3 = e[3]; x4 = e[4];
        }
        u16x4 ev;
        #pragma unroll
        for (int j = 0; j < 4; ++j) {
            float a = bemb[j];
            a += wemb[j][0] * x0; a += wemb[j][1] * x1; a += wemb[j][2] * x2;
            a += wemb[j][3] * x3; a += wemb[j][4] * x4;
            ev[j] = f2bf(fmaxf(a, 0.f));
        }
        *(u16x4*)((char*)&emb_lds[b][0] + ebyte) = ev;
    };

    __syncthreads();   // ext + valid + h0 ready
    emb_store(0, 0);
    __syncthreads();   // emb[0] ready

    // A-frag: row = lane&15, logical byte = (row<<8) + (lane>>4)*16 + kt*64;
    // XOR the (row&7)<<4 key onto the FULL offset (key bit 6 overlaps kt*64!).
    const int arow  = lane & 15;
    const int akey  = (arow & 7) << 4;
    const int abase = (arow << 8) + ((lane >> 4) << 4);
    const int crow  = (lane >> 4) << 2;   // C/D map (m89): row=(lane>>4)*4+i, col=lane&15

    float c0 = 0.f, c1 = 0.f, c2 = 0.f, c3 = 0.f;

    for (int s = 0; s < S_LEN; ++s) {
        const char* eb = (const char*)&emb_lds[s & 1][0];
        const char* hb = (const char*)&h_lds[s & 1][0];

        f32x4 a0 = {bia[0], bia[0], bia[0], bia[0]};
        f32x4 a1 = {bia[1], bia[1], bia[1], bia[1]};
        f32x4 a2 = {bia[2], bia[2], bia[2], bia[2]};
        f32x4 a3 = {bia[3], bia[3], bia[3], bia[3]};

        #pragma unroll
        for (int kt = 0; kt < 4; ++kt) {
            const int aoff = (abase + kt * 64) ^ akey;    // full-offset XOR (the fix)
            bf16x8 ae = *(const bf16x8*)(eb + aoff);
            bf16x8 ah = *(const bf16x8*)(hb + aoff);
            a0 = __builtin_amdgcn_mfma_f32_16x16x32_bf16(ae, wih[0][kt], a0, 0, 0, 0);
            a0 = __builtin_amdgcn_mfma_f32_16x16x32_bf16(ah, whh[0][kt], a0, 0, 0, 0);
            a1 = __builtin_amdgcn_mfma_f32_16x16x32_bf16(ae, wih[1][kt], a1, 0, 0, 0);
            a1 = __builtin_amdgcn_mfma_f32_16x16x32_bf16(ah, whh[1][kt], a1, 0, 0, 0);
            a2 = __builtin_amdgcn_mfma_f32_16x16x32_bf16(ae, wih[2][kt], a2, 0, 0, 0);
            a2 = __builtin_amdgcn_mfma_f32_16x16x32_bf16(ah, whh[2][kt], a2, 0, 0, 0);
            a3 = __builtin_amdgcn_mfma_f32_16x16x32_bf16(ae, wih[3][kt], a3, 0, 0, 0);
            a3 = __builtin_amdgcn_mfma_f32_16x16x32_bf16(ah, whh[3][kt], a3, 0, 0, 0);
        }

        // next-step emb: independent of MFMA results, fills their latency
        if (s + 1 < S_LEN) emb_store(s + 1, (s + 1) & 1);

        // ---- in-register LSTM cell for (rows crow..crow+3, hcol) ----
        char* hn = (char*)&h_lds[(s + 1) & 1][0];
        float hv0, hv1, hv2, hv3;
        c0 = sigf(a1[0]) * c0 + sigf(a0[0]) * thf(a2[0]);  hv0 = sigf(a3[0]) * thf(c0);
        c1 = sigf(a1[1]) * c1 + sigf(a0[1]) * thf(a2[1]);  hv1 = sigf(a3[1]) * thf(c1);
        c2 = sigf(a1[2]) * c2 + sigf(a0[2]) * thf(a2[2]);  hv2 = sigf(a3[2]) * thf(c2);
        c3 = sigf(a1[3]) * c3 + sigf(a0[3]) * thf(a2[3]);  hv3 = sigf(a3[3]) * thf(c3);

        #pragma unroll
        for (int i = 0; i < 4; ++i) {
            const float hvi = (i == 0) ? hv0 : (i == 1) ? hv1 : (i == 2) ? hv2 : hv3;
            const int r = crow + i;
            const int byte = ((r << 8) + (hcol << 1)) ^ ((r & 7) << 4);
            *(unsigned short*)(hn + byte) = f2bf(hvi);
        }

        if (s == S_LEN - 1) {
            #pragma unroll
            for (int i = 0; i < 4; ++i) {
                const float hvi = (i == 0) ? hv0 : (i == 1) ? hv1 : (i == 2) ? hv2 : hv3;
                const int r = crow + i;
                if (r < ROWS && row0 + r < BL)
                    out[(size_t)(row0 + r) * H_DIM + hcol] = hvi;
            }
        }
        __syncthreads();   // the ONE barrier: step-s writes visible, step-s reads done
    }
}

extern "C" void kernel_launch(void* const* d_in, const int* in_sizes, int n_in,
                              void* d_out, int out_size, void* d_ws, size_t ws_size,
                              hipStream_t stream) {
    const float* lanes = (const float*)d_in[1];
    const float* W_emb = (const float*)d_in[2];
    const float* b_emb = (const float*)d_in[3];
    const float* W_ih  = (const float*)d_in[4];
    const float* W_hh  = (const float*)d_in[5];
    const float* b_ih  = (const float*)d_in[6];
    const float* b_hh  = (const float*)d_in[7];
    float* out = (float*)d_out;

    const int BL   = in_sizes[1] / (2 * S_LEN);   // 2560
    const int grid = (BL + ROWS - 1) / ROWS;      // 256 blocks -> 1 per CU

    lane_lstm<<<dim3(grid), dim3(BLOCK_T), 0, stream>>>(
        lanes, W_emb, b_emb, W_ih, W_hh, b_ih, b_hh, out, BL);
}

// Round 4
// 128.741 us; speedup vs baseline: 1.6058x; 1.1375x over previous
//
#include <hip/hip_runtime.h>
#include <stdint.h>

#define S_LEN 80
#define H_DIM 128
#define ROWS 10      // real lane rows per block (2560 = 256 blocks * 10)
#define MROWS 16     // padded MFMA M-tile
#define BLOCK_T 512  // 8 waves

typedef __bf16 bf16x8 __attribute__((ext_vector_type(8)));
typedef unsigned short u16x8 __attribute__((ext_vector_type(8)));
typedef unsigned short u16x4 __attribute__((ext_vector_type(4)));
typedef float f32x4 __attribute__((ext_vector_type(4)));

__device__ __forceinline__ unsigned short f2bf(float f) {
    uint32_t u = __builtin_bit_cast(uint32_t, f);
    u += 0x7FFFu + ((u >> 16) & 1u);   // round-to-nearest-even
    return (unsigned short)(u >> 16);
}
__device__ __forceinline__ float sigf(float x) {
    return __builtin_amdgcn_rcpf(1.0f + __expf(-x));
}
__device__ __forceinline__ float thf(float x) {
    return 2.0f * __builtin_amdgcn_rcpf(1.0f + __expf(-2.0f * x)) - 1.0f;
}

// One block = 10 lane rows through 80 LSTM steps. 8 waves; wave w owns hcols
// [w*16, w*16+16) with ALL FOUR gates (N-tiles at cols g*128 + w*16) so the
// cell update is wave-local in registers. One barrier per step, double-buffered
// h/emb LDS.
//
// ROUND-4 FIX: W_ih/W_hh fragments (32 x 4 regs = 128 regs/wave) are pinned
// into AGPRs via asm "+a" constraints. Round 3 left them to the allocator,
// which spilled all 128 to scratch (WRITE_SIZE showed 64 MB = 512 B/thread of
// dirty scratch evictions) and re-loaded B-operands from scratch inside the
// 80-step loop. gfx950 MFMA reads B directly from AGPRs (unified file).
//
// Swizzle discipline: key = (row&7)<<4 spans BITS 4-6 -> XOR onto the FULL
// logical byte offset (incl. kt*64, bits 6-7), never onto a pre-XORed base.
__global__ __launch_bounds__(BLOCK_T, 2)
void lane_lstm(const float* __restrict__ lanes,
               const float* __restrict__ W_emb, const float* __restrict__ b_emb,
               const float* __restrict__ W_ih,  const float* __restrict__ W_hh,
               const float* __restrict__ b_ih,  const float* __restrict__ b_hh,
               float* __restrict__ out, int BL)
{
    __shared__ __align__(16) float ext_lds[S_LEN * ROWS * 5];           // 16000 B
    __shared__ __align__(16) unsigned short emb_lds[2][MROWS * H_DIM];  // 2x4096 B
    __shared__ __align__(16) unsigned short h_lds[2][MROWS * H_DIM];    // 2x4096 B
    __shared__ int valid_lds[MROWS];

    const int t    = threadIdx.x;
    const int lane = t & 63;
    const int wv   = t >> 6;
    const int row0 = blockIdx.x * ROWS;

    if (t < MROWS) valid_lds[t] = 1;
    {   // h0 = 0 (buffer 0): 512 threads x 8 B = 4096 B
        u16x4 z = {0, 0, 0, 0};
        *(u16x4*)((char*)&h_lds[0][0] + t * 8) = z;
    }
    __syncthreads();   // valid init visible before NaN-clears below

    // ---- ext features (x,y,dx,dy,yaw); consecutive p -> consecutive r (coalesced) ----
    for (int p = t; p < S_LEN * ROWS; p += BLOCK_T) {
        int s = p / ROWS;
        int r = p - s * ROWS;
        int bl = row0 + r;
        float x = 0.f, y = 0.f, dx = 0.f, dy = 0.f;
        if (bl < BL) {
            const float* lp = lanes + ((size_t)s * BL + bl) * 2;
            x = lp[0]; y = lp[1];
            if (s > 0) {
                const float* lq = lanes + ((size_t)(s - 1) * BL + bl) * 2;
                dx = x - lq[0]; dy = y - lq[1];
            }
            if (__builtin_isnan(x) || __builtin_isnan(y)) valid_lds[r] = 0;
        }
        float* e = &ext_lds[p * 5];
        e[0] = x; e[1] = y; e[2] = dx; e[3] = dy; e[4] = atan2f(y, x);
    }

    // ---- wave-owned weight B-frags (bf16 bit-patterns in f32x4), AGPR-pinned ----
    // B-frag: col = g*128 + wv*16 + (lane&15), k = kt*32 + (lane>>4)*8 + j.
    // Same (lane,j)->k map as A-frags => HW k-permutation cancels.
    const int hcol = wv * 16 + (lane & 15);
    const int kb0  = (lane >> 4) << 3;
    f32x4 wih[4][4], whh[4][4];
    float bia[4];
    #pragma unroll
    for (int g = 0; g < 4; ++g) {
        bia[g] = b_ih[g * H_DIM + hcol] + b_hh[g * H_DIM + hcol];
        #pragma unroll
        for (int kt = 0; kt < 4; ++kt) {
            const float* pa = &W_ih[(size_t)(g * H_DIM + hcol) * H_DIM + kt * 32 + kb0];
            const float* pb = &W_hh[(size_t)(g * H_DIM + hcol) * H_DIM + kt * 32 + kb0];
            u16x8 ta, tb;
            #pragma unroll
            for (int j = 0; j < 8; ++j) { ta[j] = f2bf(pa[j]); tb[j] = f2bf(pb[j]); }
            wih[g][kt] = __builtin_bit_cast(f32x4, ta);
            whh[g][kt] = __builtin_bit_cast(f32x4, tb);
        }
    }
    // Pin every fragment into the AGPR file (prevents scratch spill; MFMA
    // consumes B straight from AGPRs on gfx950).
    #pragma unroll
    for (int g = 0; g < 4; ++g) {
        #pragma unroll
        for (int kt = 0; kt < 4; ++kt) {
            asm volatile("" : "+a"(wih[g][kt]));
            asm volatile("" : "+a"(whh[g][kt]));
        }
    }

    // ---- per-thread emb constants (thread t -> row t>>5, hcols (t&31)*4..+3) ----
    const int er  = t >> 5;
    const int ec0 = (t & 31) << 2;
    float wemb[4][5], bemb[4];
    #pragma unroll
    for (int j = 0; j < 4; ++j) {
        #pragma unroll
        for (int d = 0; d < 5; ++d) wemb[j][d] = W_emb[(ec0 + j) * 5 + d];
        bemb[j] = b_emb[ec0 + j];
    }
    const int ebyte = ((er << 8) + (ec0 << 1)) ^ ((er & 7) << 4);   // full-offset XOR

    auto emb_store = [&](int s, int b) {
        float x0 = 0.f, x1 = 0.f, x2 = 0.f, x3 = 0.f, x4 = 0.f;
        if (er < ROWS && valid_lds[er] && row0 + er < BL) {
            const float* e = &ext_lds[(s * ROWS + er) * 5];
            x0 = e[0]; x1 = e[1]; x2 = e[2]; x3 = e[3]; x4 = e[4];
        }
        u16x4 ev;
        #pragma unroll
        for (int j = 0; j < 4; ++j) {
            float a = bemb[j];
            a += wemb[j][0] * x0; a += wemb[j][1] * x1; a += wemb[j][2] * x2;
            a += wemb[j][3] * x3; a += wemb[j][4] * x4;
            ev[j] = f2bf(fmaxf(a, 0.f));
        }
        *(u16x4*)((char*)&emb_lds[b][0] + ebyte) = ev;
    };

    __syncthreads();   // ext + valid + h0 ready
    emb_store(0, 0);
    __syncthreads();   // emb[0] ready

    // A-frag: row = lane&15, logical byte = (row<<8) + (lane>>4)*16 + kt*64;
    // XOR the (row&7)<<4 key onto the FULL offset (key bit 6 overlaps kt*64!).
    const int arow  = lane & 15;
    const int akey  = (arow & 7) << 4;
    const int abase = (arow << 8) + ((lane >> 4) << 4);
    const int crow  = (lane >> 4) << 2;   // C/D map (m89): row=(lane>>4)*4+i, col=lane&15

    float c0 = 0.f, c1 = 0.f, c2 = 0.f, c3 = 0.f;

    for (int s = 0; s < S_LEN; ++s) {
        const char* eb = (const char*)&emb_lds[s & 1][0];
        const char* hb = (const char*)&h_lds[s & 1][0];

        f32x4 a0 = {bia[0], bia[0], bia[0], bia[0]};
        f32x4 a1 = {bia[1], bia[1], bia[1], bia[1]};
        f32x4 a2 = {bia[2], bia[2], bia[2], bia[2]};
        f32x4 a3 = {bia[3], bia[3], bia[3], bia[3]};

        #pragma unroll
        for (int kt = 0; kt < 4; ++kt) {
            const int aoff = (abase + kt * 64) ^ akey;    // full-offset XOR
            bf16x8 ae = *(const bf16x8*)(eb + aoff);
            bf16x8 ah = *(const bf16x8*)(hb + aoff);
            a0 = __builtin_amdgcn_mfma_f32_16x16x32_bf16(ae, __builtin_bit_cast(bf16x8, wih[0][kt]), a0, 0, 0, 0);
            a0 = __builtin_amdgcn_mfma_f32_16x16x32_bf16(ah, __builtin_bit_cast(bf16x8, whh[0][kt]), a0, 0, 0, 0);
            a1 = __builtin_amdgcn_mfma_f32_16x16x32_bf16(ae, __builtin_bit_cast(bf16x8, wih[1][kt]), a1, 0, 0, 0);
            a1 = __builtin_amdgcn_mfma_f32_16x16x32_bf16(ah, __builtin_bit_cast(bf16x8, whh[1][kt]), a1, 0, 0, 0);
            a2 = __builtin_amdgcn_mfma_f32_16x16x32_bf16(ae, __builtin_bit_cast(bf16x8, wih[2][kt]), a2, 0, 0, 0);
            a2 = __builtin_amdgcn_mfma_f32_16x16x32_bf16(ah, __builtin_bit_cast(bf16x8, whh[2][kt]), a2, 0, 0, 0);
            a3 = __builtin_amdgcn_mfma_f32_16x16x32_bf16(ae, __builtin_bit_cast(bf16x8, wih[3][kt]), a3, 0, 0, 0);
            a3 = __builtin_amdgcn_mfma_f32_16x16x32_bf16(ah, __builtin_bit_cast(bf16x8, whh[3][kt]), a3, 0, 0, 0);
        }

        // next-step emb: independent of MFMA results, fills their latency
        if (s + 1 < S_LEN) emb_store(s + 1, (s + 1) & 1);

        // ---- in-register LSTM cell for (rows crow..crow+3, hcol) ----
        char* hn = (char*)&h_lds[(s + 1) & 1][0];
        float hv0, hv1, hv2, hv3;
        c0 = sigf(a1[0]) * c0 + sigf(a0[0]) * thf(a2[0]);  hv0 = sigf(a3[0]) * thf(c0);
        c1 = sigf(a1[1]) * c1 + sigf(a0[1]) * thf(a2[1]);  hv1 = sigf(a3[1]) * thf(c1);
        c2 = sigf(a1[2]) * c2 + sigf(a0[2]) * thf(a2[2]);  hv2 = sigf(a3[2]) * thf(c2);
        c3 = sigf(a1[3]) * c3 + sigf(a0[3]) * thf(a2[3]);  hv3 = sigf(a3[3]) * thf(c3);

        #pragma unroll
        for (int i = 0; i < 4; ++i) {
            const float hvi = (i == 0) ? hv0 : (i == 1) ? hv1 : (i == 2) ? hv2 : hv3;
            const int r = crow + i;
            const int byte = ((r << 8) + (hcol << 1)) ^ ((r & 7) << 4);
            *(unsigned short*)(hn + byte) = f2bf(hvi);
        }

        if (s == S_LEN - 1) {
            #pragma unroll
            for (int i = 0; i < 4; ++i) {
                const float hvi = (i == 0) ? hv0 : (i == 1) ? hv1 : (i == 2) ? hv2 : hv3;
                const int r = crow + i;
                if (r < ROWS && row0 + r < BL)
                    out[(size_t)(row0 + r) * H_DIM + hcol] = hvi;
            }
        }
        __syncthreads();   // the ONE barrier: step-s writes visible, step-s reads done
    }
}

extern "C" void kernel_launch(void* const* d_in, const int* in_sizes, int n_in,
                              void* d_out, int out_size, void* d_ws, size_t ws_size,
                              hipStream_t stream) {
    const float* lanes = (const float*)d_in[1];
    const float* W_emb = (const float*)d_in[2];
    const float* b_emb = (const float*)d_in[3];
    const float* W_ih  = (const float*)d_in[4];
    const float* W_hh  = (const float*)d_in[5];
    const float* b_ih  = (const float*)d_in[6];
    const float* b_hh  = (const float*)d_in[7];
    float* out = (float*)d_out;

    const int BL   = in_sizes[1] / (2 * S_LEN);   // 2560
    const int grid = (BL + ROWS - 1) / ROWS;      // 256 blocks -> 1 per CU

    lane_lstm<<<dim3(grid), dim3(BLOCK_T), 0, stream>>>(
        lanes, W_emb, b_emb, W_ih, W_hh, b_ih, b_hh, out, BL);
}

// Round 5
// 116.654 us; speedup vs baseline: 1.7722x; 1.1036x over previous
//
#include <hip/hip_runtime.h>
#include <stdint.h>

#define S_LEN 80
#define H_DIM 128
#define ROWS 10      // real lane rows per block (2560 = 256 blocks * 10)
#define MROWS 16     // padded MFMA M-tile
#define BLOCK_T 512  // 8 waves

#define NL2E  (-1.44269504088896f)   // -log2(e)
#define N2L2E (-2.88539008177793f)   // -2*log2(e)

typedef __bf16 bf16x8 __attribute__((ext_vector_type(8)));
typedef unsigned short u16x8 __attribute__((ext_vector_type(8)));
typedef unsigned short u16x4 __attribute__((ext_vector_type(4)));
typedef float f32x4 __attribute__((ext_vector_type(4)));

// sigmoid(x) with y = -log2e*x already applied via pre-scaled weights
__device__ __forceinline__ float sigy(float y) {
    return __builtin_amdgcn_rcpf(1.0f + __builtin_amdgcn_exp2f(y));
}
// tanh(x) with y = -2*log2e*x already applied
__device__ __forceinline__ float tanhy(float y) {
    return 2.0f * __builtin_amdgcn_rcpf(1.0f + __builtin_amdgcn_exp2f(y)) - 1.0f;
}
__device__ __forceinline__ unsigned short bfbits(float f) {
    return __builtin_bit_cast(unsigned short, (__bf16)f);   // HW RNE cvt
}

// D,A,B,C with C==D (accumulate in place). B comes straight from AGPRs —
// no a->v copies; A is the ds_read dest (VGPR); acc lives in VGPRs.
#define MFMA16(acc, va, wb) \
    asm("v_mfma_f32_16x16x32_bf16 %0, %1, %2, %0" : "+v"(acc) : "v"(va), "a"(wb))

// One block = 10 lane rows through 80 LSTM steps. 8 waves; wave w owns hcols
// [w*16, w*16+16) with ALL FOUR gates so the cell is wave-local in registers.
// One barrier per step, double-buffered h/emb LDS.
//
// R5 structure: the input projection xp[s+1] = emb[s+1]@W_ih^T is computed
// DURING step s (it does not depend on h) — it fills the MFMA pipe while the
// cell's transcendental chain runs, and the serial hh chain is only 4 deep.
// Weights pre-scaled by -log2e (g gate: -2log2e) => sig/tanh = rcp(1+exp2(y)).
//
// Swizzle discipline: key = (row&7)<<4 spans BITS 4-6 -> XOR onto the FULL
// logical byte offset (incl. kt*64, bits 6-7), never onto a pre-XORed base.
__global__ __launch_bounds__(BLOCK_T, 2)
void lane_lstm(const float* __restrict__ lanes,
               const float* __restrict__ W_emb, const float* __restrict__ b_emb,
               const float* __restrict__ W_ih,  const float* __restrict__ W_hh,
               const float* __restrict__ b_ih,  const float* __restrict__ b_hh,
               float* __restrict__ out, int BL)
{
    __shared__ __align__(16) float ext_lds[S_LEN * ROWS * 5];           // 16000 B
    __shared__ __align__(16) unsigned short emb_lds[2][MROWS * H_DIM];  // 2x4096 B
    __shared__ __align__(16) unsigned short h_lds[2][MROWS * H_DIM];    // 2x4096 B
    __shared__ int valid_lds[MROWS];

    const int t    = threadIdx.x;
    const int lane = t & 63;
    const int wv   = t >> 6;
    const int row0 = blockIdx.x * ROWS;

    if (t < MROWS) valid_lds[t] = 1;
    {   // h0 = 0 (buffer 0)
        u16x4 z = {0, 0, 0, 0};
        *(u16x4*)((char*)&h_lds[0][0] + t * 8) = z;
    }
    __syncthreads();

    // ---- ext features (x,y,dx,dy,yaw) ----
    for (int p = t; p < S_LEN * ROWS; p += BLOCK_T) {
        int s = p / ROWS;
        int r = p - s * ROWS;
        int bl = row0 + r;
        float x = 0.f, y = 0.f, dx = 0.f, dy = 0.f;
        if (bl < BL) {
            const float* lp = lanes + ((size_t)s * BL + bl) * 2;
            x = lp[0]; y = lp[1];
            if (s > 0) {
                const float* lq = lanes + ((size_t)(s - 1) * BL + bl) * 2;
                dx = x - lq[0]; dy = y - lq[1];
            }
            if (__builtin_isnan(x) || __builtin_isnan(y)) valid_lds[r] = 0;
        }
        float* e = &ext_lds[p * 5];
        e[0] = x; e[1] = y; e[2] = dx; e[3] = dy; e[4] = atan2f(y, x);
    }

    // ---- wave-owned weight B-frags, PRE-SCALED, AGPR-pinned ----
    // B-frag: col = g*128 + wv*16 + (lane&15), k = kt*32 + (lane>>4)*8 + j.
    // Gate scale: i,f,o -> -log2e ; g -> -2log2e (exp2-direct nonlinearities).
    const int hcol = wv * 16 + (lane & 15);
    const int kb0  = (lane >> 4) << 3;
    f32x4 wih[4][4], whh[4][4];
    float bia[4];
    #pragma unroll
    for (int g = 0; g < 4; ++g) {
        const float sc = (g == 2) ? N2L2E : NL2E;
        bia[g] = (b_ih[g * H_DIM + hcol] + b_hh[g * H_DIM + hcol]) * sc;
        #pragma unroll
        for (int kt = 0; kt < 4; ++kt) {
            const float* pa = &W_ih[(size_t)(g * H_DIM + hcol) * H_DIM + kt * 32 + kb0];
            const float* pb = &W_hh[(size_t)(g * H_DIM + hcol) * H_DIM + kt * 32 + kb0];
            u16x8 ta, tb;
            #pragma unroll
            for (int j = 0; j < 8; ++j) { ta[j] = bfbits(pa[j] * sc); tb[j] = bfbits(pb[j] * sc); }
            wih[g][kt] = __builtin_bit_cast(f32x4, ta);
            whh[g][kt] = __builtin_bit_cast(f32x4, tb);
        }
    }
    #pragma unroll
    for (int g = 0; g < 4; ++g) {
        #pragma unroll
        for (int kt = 0; kt < 4; ++kt) {
            asm volatile("" : "+a"(wih[g][kt]));
            asm volatile("" : "+a"(whh[g][kt]));
        }
    }

    // ---- per-thread emb constants (thread t -> row t>>5, hcols (t&31)*4..+3) ----
    const int er  = t >> 5;
    const int ec0 = (t & 31) << 2;
    float wemb[4][5], bemb[4];
    #pragma unroll
    for (int j = 0; j < 4; ++j) {
        #pragma unroll
        for (int d = 0; d < 5; ++d) wemb[j][d] = W_emb[(ec0 + j) * 5 + d];
        bemb[j] = b_emb[ec0 + j];
    }
    const int ebyte = ((er << 8) + (ec0 << 1)) ^ ((er & 7) << 4);

    auto emb_store = [&](int s, int b) {
        float x0 = 0.f, x1 = 0.f, x2 = 0.f, x3 = 0.f, x4 = 0.f;
        if (er < ROWS && valid_lds[er] && row0 + er < BL) {
            const float* e = &ext_lds[(s * ROWS + er) * 5];
            x0 = e[0]; x1 = e[1]; x2 = e[2]; x3 = e[3]; x4 = e[4];
        }
        u16x4 ev;
        #pragma unroll
        for (int j = 0; j < 4; ++j) {
            float a = bemb[j];
            a += wemb[j][0] * x0; a += wemb[j][1] * x1; a += wemb[j][2] * x2;
            a += wemb[j][3] * x3; a += wemb[j][4] * x4;
            ev[j] = bfbits(fmaxf(a, 0.f));
        }
        *(u16x4*)((char*)&emb_lds[b][0] + ebyte) = ev;
    };

    // A-frag: row = lane&15, logical byte = (row<<8) + (lane>>4)*16 + kt*64;
    // XOR the (row&7)<<4 key onto the FULL offset.
    const int arow  = lane & 15;
    const int akey  = (arow & 7) << 4;
    const int abase = (arow << 8) + ((lane >> 4) << 4);
    const int crow  = (lane >> 4) << 2;   // C/D (m89): row=(lane>>4)*4+i, col=lane&15

    __syncthreads();       // ext + valid + h0 ready
    emb_store(0, 0);
    __syncthreads();       // emb[0] visible

    // ---- prologue: xp = bias + emb[0] @ W_ih^T ----
    f32x4 xp0 = {bia[0], bia[0], bia[0], bia[0]};
    f32x4 xp1 = {bia[1], bia[1], bia[1], bia[1]};
    f32x4 xp2 = {bia[2], bia[2], bia[2], bia[2]};
    f32x4 xp3 = {bia[3], bia[3], bia[3], bia[3]};
    {
        const char* eb = (const char*)&emb_lds[0][0];
        #pragma unroll
        for (int kt = 0; kt < 4; ++kt) {
            bf16x8 ae = *(const bf16x8*)(eb + ((abase + kt * 64) ^ akey));
            MFMA16(xp0, ae, wih[0][kt]);
            MFMA16(xp1, ae, wih[1][kt]);
            MFMA16(xp2, ae, wih[2][kt]);
            MFMA16(xp3, ae, wih[3][kt]);
        }
    }
    emb_store(1, 1);
    __syncthreads();       // emb[1] visible

    float c0 = 0.f, c1 = 0.f, c2 = 0.f, c3 = 0.f;

    for (int s = 0; s < S_LEN; ++s) {
        const char* hb = (const char*)&h_lds[s & 1][0];
        const char* en = (const char*)&emb_lds[(s + 1) & 1][0];   // emb[s+1]

        // ---- hh GEMM: gates = xp[s] + h[s] @ W_hh^T (serial path, 4-deep) ----
        bf16x8 ah0 = *(const bf16x8*)(hb + ((abase + 0 * 64) ^ akey));
        bf16x8 ah1 = *(const bf16x8*)(hb + ((abase + 1 * 64) ^ akey));
        bf16x8 ah2 = *(const bf16x8*)(hb + ((abase + 2 * 64) ^ akey));
        bf16x8 ah3 = *(const bf16x8*)(hb + ((abase + 3 * 64) ^ akey));
        f32x4 g0 = xp0, g1 = xp1, g2 = xp2, g3 = xp3;
        MFMA16(g0, ah0, whh[0][0]); MFMA16(g1, ah0, whh[1][0]);
        MFMA16(g2, ah0, whh[2][0]); MFMA16(g3, ah0, whh[3][0]);
        MFMA16(g0, ah1, whh[0][1]); MFMA16(g1, ah1, whh[1][1]);
        MFMA16(g2, ah1, whh[2][1]); MFMA16(g3, ah1, whh[3][1]);
        MFMA16(g0, ah2, whh[0][2]); MFMA16(g1, ah2, whh[1][2]);
        MFMA16(g2, ah2, whh[2][2]); MFMA16(g3, ah2, whh[3][2]);
        MFMA16(g0, ah3, whh[0][3]); MFMA16(g1, ah3, whh[1][3]);
        MFMA16(g2, ah3, whh[2][3]); MFMA16(g3, ah3, whh[3][3]);

        // ---- ih GEMM for step s+1 (independent of h — overlaps the cell) ----
        if (s + 1 < S_LEN) {
            bf16x8 ae0 = *(const bf16x8*)(en + ((abase + 0 * 64) ^ akey));
            bf16x8 ae1 = *(const bf16x8*)(en + ((abase + 1 * 64) ^ akey));
            bf16x8 ae2 = *(const bf16x8*)(en + ((abase + 2 * 64) ^ akey));
            bf16x8 ae3 = *(const bf16x8*)(en + ((abase + 3 * 64) ^ akey));
            xp0 = (f32x4){bia[0], bia[0], bia[0], bia[0]};
            xp1 = (f32x4){bia[1], bia[1], bia[1], bia[1]};
            xp2 = (f32x4){bia[2], bia[2], bia[2], bia[2]};
            xp3 = (f32x4){bia[3], bia[3], bia[3], bia[3]};
            MFMA16(xp0, ae0, wih[0][0]); MFMA16(xp1, ae0, wih[1][0]);
            MFMA16(xp2, ae0, wih[2][0]); MFMA16(xp3, ae0, wih[3][0]);
            MFMA16(xp0, ae1, wih[0][1]); MFMA16(xp1, ae1, wih[1][1]);
            MFMA16(xp2, ae1, wih[2][1]); MFMA16(xp3, ae1, wih[3][1]);
            MFMA16(xp0, ae2, wih[0][2]); MFMA16(xp1, ae2, wih[1][2]);
            MFMA16(xp2, ae2, wih[2][2]); MFMA16(xp3, ae2, wih[3][2]);
            MFMA16(xp0, ae3, wih[0][3]); MFMA16(xp1, ae3, wih[1][3]);
            MFMA16(xp2, ae3, wih[2][3]); MFMA16(xp3, ae3, wih[3][3]);
            if (s + 2 < S_LEN) emb_store(s + 2, s & 1);
        }

        // ---- in-register LSTM cell (rows crow..crow+3, col hcol) ----
        // g0=i, g1=f, g2=g(tanh, pre-scaled -2log2e), g3=o
        char* hn = (char*)&h_lds[(s + 1) & 1][0];
        float hv0, hv1, hv2, hv3;
        c0 = sigy(g1[0]) * c0 + sigy(g0[0]) * tanhy(g2[0]);  hv0 = sigy(g3[0]) * tanhy(c0 * N2L2E);
        c1 = sigy(g1[1]) * c1 + sigy(g0[1]) * tanhy(g2[1]);  hv1 = sigy(g3[1]) * tanhy(c1 * N2L2E);
        c2 = sigy(g1[2]) * c2 + sigy(g0[2]) * tanhy(g2[2]);  hv2 = sigy(g3[2]) * tanhy(c2 * N2L2E);
        c3 = sigy(g1[3]) * c3 + sigy(g0[3]) * tanhy(g2[3]);  hv3 = sigy(g3[3]) * tanhy(c3 * N2L2E);

        #pragma unroll
        for (int i = 0; i < 4; ++i) {
            const float hvi = (i == 0) ? hv0 : (i == 1) ? hv1 : (i == 2) ? hv2 : hv3;
            const int r = crow + i;
            const int byte = ((r << 8) + (hcol << 1)) ^ ((r & 7) << 4);
            *(unsigned short*)(hn + byte) = bfbits(hvi);
        }

        if (s == S_LEN - 1) {
            #pragma unroll
            for (int i = 0; i < 4; ++i) {
                const float hvi = (i == 0) ? hv0 : (i == 1) ? hv1 : (i == 2) ? hv2 : hv3;
                const int r = crow + i;
                if (r < ROWS && row0 + r < BL)
                    out[(size_t)(row0 + r) * H_DIM + hcol] = hvi;
            }
        }
        __syncthreads();   // one barrier/step
    }
}

extern "C" void kernel_launch(void* const* d_in, const int* in_sizes, int n_in,
                              void* d_out, int out_size, void* d_ws, size_t ws_size,
                              hipStream_t stream) {
    const float* lanes = (const float*)d_in[1];
    const float* W_emb = (const float*)d_in[2];
    const float* b_emb = (const float*)d_in[3];
    const float* W_ih  = (const float*)d_in[4];
    const float* W_hh  = (const float*)d_in[5];
    const float* b_ih  = (const float*)d_in[6];
    const float* b_hh  = (const float*)d_in[7];
    float* out = (float*)d_out;

    const int BL   = in_sizes[1] / (2 * S_LEN);   // 2560
    const int grid = (BL + ROWS - 1) / ROWS;      // 256 blocks -> 1 per CU

    lane_lstm<<<dim3(grid), dim3(BLOCK_T), 0, stream>>>(
        lanes, W_emb, b_emb, W_ih, W_hh, b_ih, b_hh, out, BL);
}